// Round 1
// baseline (229.957 us; speedup 1.0000x reference)
//
#include <hip/hip_runtime.h>

// GroupSort: x[32,256,64,64] fp32. For each channel pair (2k, 2k+1):
//   d = x[2k] - x[2k+1]; r = relu(d); out[2k] = x[2k] - r; out[2k+1] = x[2k+1] + r
// (== pairwise min/max, but we keep the exact reference arithmetic).
// Pure memory-bound elementwise op: 128 MiB in + 128 MiB out.
//
// Layout: plane = H*W = 4096 floats = 1024 float4. Pair stride = 2 planes.
// Thread t (one float4 per plane side): pair = t>>10, within = t&1023.

__global__ __launch_bounds__(256) void groupsort_kernel(
    const float4* __restrict__ x, float4* __restrict__ out) {
    const long t = (long)blockIdx.x * blockDim.x + threadIdx.x; // 0..4194303
    const long pair   = t >> 10;         // which channel pair plane
    const long within = t & 1023;        // float4 within the 4096-float plane
    const long even_off = pair * 2048 + within; // float4 units
    const long odd_off  = even_off + 1024;

    const float4 a = x[even_off];
    const float4 b = x[odd_off];

    float4 lo, hi;
    {
        float d = a.x - b.x; float r = d > 0.0f ? d : 0.0f;
        lo.x = a.x - r; hi.x = b.x + r;
    }
    {
        float d = a.y - b.y; float r = d > 0.0f ? d : 0.0f;
        lo.y = a.y - r; hi.y = b.y + r;
    }
    {
        float d = a.z - b.z; float r = d > 0.0f ? d : 0.0f;
        lo.z = a.z - r; hi.z = b.z + r;
    }
    {
        float d = a.w - b.w; float r = d > 0.0f ? d : 0.0f;
        lo.w = a.w - r; hi.w = b.w + r;
    }

    out[even_off] = lo;
    out[odd_off]  = hi;
}

extern "C" void kernel_launch(void* const* d_in, const int* in_sizes, int n_in,
                              void* d_out, int out_size, void* d_ws, size_t ws_size,
                              hipStream_t stream) {
    const float4* x = (const float4*)d_in[0];
    float4* out = (float4*)d_out;
    // total float4 per side: 32*128 pairs * 1024 = 4,194,304
    const int threads = 256;
    const int blocks = 4194304 / threads; // 16384
    groupsort_kernel<<<blocks, threads, 0, stream>>>(x, out);
}

// Round 3
// 228.532 us; speedup vs baseline: 1.0062x; 1.0062x over previous
//
#include <hip/hip_runtime.h>

// GroupSort: x[32,256,64,64] fp32. For each channel pair (2k, 2k+1):
//   d = x[2k] - x[2k+1]; r = relu(d); out[2k] = x[2k] - r; out[2k+1] = x[2k+1] + r
// Pure streaming elementwise op: 128 MiB in + 128 MiB out, zero reuse.
// -> nontemporal loads/stores (nt flag) to avoid cache write-allocate churn.
//
// NOTE: __builtin_nontemporal_* requires a NATIVE clang vector type, not
// HIP_vector_type<float,4> — hence the ext_vector_type typedef.
//
// Layout: plane = H*W = 4096 floats = 1024 float4. Pair stride = 2 planes.
// Each thread handles TWO float4 slots per plane side (64 B load / 64 B store).

typedef float f32x4 __attribute__((ext_vector_type(4)));

__device__ __forceinline__ f32x4 nt_load4(const f32x4* p) {
    return __builtin_nontemporal_load(p);
}
__device__ __forceinline__ void nt_store4(f32x4* p, f32x4 v) {
    __builtin_nontemporal_store(v, p);
}

__device__ __forceinline__ void pair_op(const f32x4 a, const f32x4 b,
                                        f32x4& lo, f32x4& hi) {
#pragma unroll
    for (int i = 0; i < 4; ++i) {
        float d = a[i] - b[i];
        float r = d > 0.0f ? d : 0.0f;
        lo[i] = a[i] - r;
        hi[i] = b[i] + r;
    }
}

__global__ __launch_bounds__(256) void groupsort_kernel(
    const f32x4* __restrict__ x, f32x4* __restrict__ out) {
    // 2,097,152 threads; each owns 2 consecutive float4 in the even plane
    // and the matching 2 in the odd plane (+1024 float4 = +16 KiB).
    const long t = (long)blockIdx.x * blockDim.x + threadIdx.x;
    const long s = t * 2;                 // first float4 slot (of 2)
    const long pair   = s >> 10;          // channel-pair index (plane pair)
    const long within = s & 1023;
    const long even_off = pair * 2048 + within;
    const long odd_off  = even_off + 1024;

    const f32x4 a0 = nt_load4(x + even_off);
    const f32x4 a1 = nt_load4(x + even_off + 1);
    const f32x4 b0 = nt_load4(x + odd_off);
    const f32x4 b1 = nt_load4(x + odd_off + 1);

    f32x4 lo0, hi0, lo1, hi1;
    pair_op(a0, b0, lo0, hi0);
    pair_op(a1, b1, lo1, hi1);

    nt_store4(out + even_off,     lo0);
    nt_store4(out + even_off + 1, lo1);
    nt_store4(out + odd_off,      hi0);
    nt_store4(out + odd_off + 1,  hi1);
}

extern "C" void kernel_launch(void* const* d_in, const int* in_sizes, int n_in,
                              void* d_out, int out_size, void* d_ws, size_t ws_size,
                              hipStream_t stream) {
    const f32x4* x = (const f32x4*)d_in[0];
    f32x4* out = (f32x4*)d_out;
    // total float4 per side: 4,194,304; 2 per thread -> 2,097,152 threads
    const int threads = 256;
    const int blocks = 2097152 / threads; // 8192
    groupsort_kernel<<<blocks, threads, 0, stream>>>(x, out);
}